// Round 1
// baseline (206.364 us; speedup 1.0000x reference)
//
#include <hip/hip_runtime.h>
#include <hip/hip_fp16.h>
#include <math.h>

// TriangleAttentionStartingNode: B=1, N=256, C=128, H=4, AC=32, fp32 in/out.
// R6: precision-lite pipeline (see prior notes). R7: lnproj latency fix —
// rocprof showed lnproj at 63us with MfmaUtil 5% / VALUBusy 17% / HBM 17%
// (all idle => latency-bound, 4.6x off its 13us BW roofline). Changes:
// (a) 64 rows/block (grid 1024), two-chunk software pipeline: both chunks'
//     act loads issued at kernel entry, chunk-1 latency hides under
//     chunk-0's MFMA+epilogue; weight frags get L1 reuse on chunk 1.
// (b) __launch_bounds__(256,4) to cap unified VGPR alloc at 128/wave
//     (88 arch + 64 acc was plausibly rounding to the 256-tier => 2-3
//     waves/SIMD, matching the ~17% occupancy counter).

#define NRES 256
#define CCH  128
#define NROWS (NRES * NRES)          // 65536
#define FACTOR 0.17677669529663687f  // 1/sqrt(32)

typedef __attribute__((ext_vector_type(8))) __bf16 bf16x8;
typedef __attribute__((ext_vector_type(4))) float f32x4;

__device__ __forceinline__ f32x4 mfma16(bf16x8 a, bf16x8 b, f32x4 c) {
    return __builtin_amdgcn_mfma_f32_16x16x32_bf16(a, b, c, 0, 0, 0);
}

union PK4 { __bf16 b[4]; uint2 u2; };
union PK2 { __bf16 b[2]; unsigned int u; };

__device__ __forceinline__ void hilo(float x, __bf16& h, __bf16& l) {
    h = (__bf16)x;
    l = (__bf16)(x - (float)h);
}

// ---------------- weight prep: pack into B-frag layout ----------------
// hi planes used by lnproj (single-MFMA GEMMs); lo planes only read for wo.
__global__ __launch_bounds__(256) void prep_kernel(
    const float* __restrict__ wq, const float* __restrict__ wk,
    const float* __restrict__ wv, const float* __restrict__ wg,
    const float* __restrict__ wo,
    __bf16* __restrict__ wph, __bf16* __restrict__ wpl)
{
    const int gid = blockIdx.x * 256 + threadIdx.x;   // 0..10239
    const int wid = gid >> 11;
    const int rem = gid & 2047;
    const int nstrip = rem >> 8;
    const int kf = (rem >> 6) & 3;
    const int lane = rem & 63;
    const int l15 = lane & 15, quad = lane >> 4;
    const float* W = (wid == 0) ? wq : (wid == 1) ? wk :
                     (wid == 2) ? wv : (wid == 3) ? wg : wo;
    const float scale = (wid == 0) ? FACTOR : 1.0f;
    bf16x8 hb, lb;
    #pragma unroll
    for (int e = 0; e < 8; ++e) {
        int k = kf * 32 + quad * 8 + e;
        int n = nstrip * 16 + l15;
        float v = W[k * CCH + n] * scale;
        __bf16 h, l; hilo(v, h, l);
        hb[e] = h; lb[e] = l;
    }
    *(bf16x8*)&wph[(size_t)gid * 8] = hb;
    *(bf16x8*)&wpl[(size_t)gid * 8] = lb;
}

// ---------------- fused LN + nb + projection (single-bf16) ----------------
// R7: 64 rows per block, two pipelined 32-row chunks.
__global__ __launch_bounds__(256, 4) void lnproj_kernel(
    const float* __restrict__ act, const float* __restrict__ ln_g,
    const float* __restrict__ ln_b, const float* __restrict__ w2d,
    const __bf16* __restrict__ wph, const float* __restrict__ bg,
    __bf16* __restrict__ qb, __bf16* __restrict__ kb,
    __bf16* __restrict__ vb, __half* __restrict__ gfh,
    float* __restrict__ nbP)
{
    __shared__ __align__(16) char smem[26112];
    __bf16* const aH = (__bf16*)smem;              // [32][136]
    const int t = threadIdx.x, w = t >> 6, lane = t & 63;
    const int l15 = lane & 15, quad = lane >> 4;
    const int r0 = blockIdx.x * 64;
    const int ridx = t >> 3, g = t & 7;            // 8 threads per row

    // Issue BOTH chunks' act loads up front. Chunk-1 data stays in regs /
    // in flight through chunk-0's MFMA phase, hiding HBM latency.
    float4 xc[2][4];
    const float* __restrict__ xp = act + (size_t)(r0 + ridx) * CCH + g * 16;
    #pragma unroll
    for (int c = 0; c < 4; ++c) xc[0][c] = *(const float4*)(xp + c * 4);
    #pragma unroll
    for (int c = 0; c < 4; ++c) xc[1][c] = *(const float4*)(xp + 32 * CCH + c * 4);

    const int tensor = w;
    const __bf16* __restrict__ Bh = wph + (size_t)tensor * 16384;
    char* const stg = smem + 8704 + w * 4352;      // per-wave [16][136] 2B plane

    #pragma unroll
    for (int chunk = 0; chunk < 2; ++chunk) {
        const int rc = r0 + chunk * 32;
        // ---- Phase A: LayerNorm + nb ----
        {
            const int grow = rc + ridx;
            float s = 0.f, sq = 0.f;
            #pragma unroll
            for (int c = 0; c < 4; ++c) {
                float4 x4 = xc[chunk][c];
                s  += (x4.x + x4.y) + (x4.z + x4.w);
                sq += x4.x * x4.x + x4.y * x4.y + x4.z * x4.z + x4.w * x4.w;
            }
            #pragma unroll
            for (int o = 1; o <= 4; o <<= 1) {
                s  += __shfl_xor(s, o, 64);
                sq += __shfl_xor(sq, o, 64);
            }
            float mu  = s * (1.0f / CCH);
            float var = fmaf(sq, 1.0f / CCH, -mu * mu);
            float rs  = rsqrtf(var + 1e-5f);
            float av[16];
            #pragma unroll
            for (int c = 0; c < 4; ++c) {
                float4 g4 = *(const float4*)&ln_g[g * 16 + c * 4];
                float4 b4 = *(const float4*)&ln_b[g * 16 + c * 4];
                float* xv = (float*)&xc[chunk][c];
                float* gv = (float*)&g4;
                float* bv = (float*)&b4;
                #pragma unroll
                for (int e = 0; e < 4; ++e)
                    av[c * 4 + e] = fmaf((xv[e] - mu) * rs, gv[e], bv[e]);
            }
            #pragma unroll
            for (int p = 0; p < 8; ++p) {
                PK2 ph;
                ph.b[0] = (__bf16)av[p * 2];
                ph.b[1] = (__bf16)av[p * 2 + 1];
                *(unsigned int*)&aH[ridx * 136 + g * 16 + p * 2] = ph.u;
            }
            float nb[4] = {0.f, 0.f, 0.f, 0.f};
            const float4* __restrict__ w2d4 = (const float4*)w2d;
            #pragma unroll
            for (int c = 0; c < 16; ++c) {
                float4 wv = w2d4[g * 16 + c];
                nb[0] = fmaf(av[c], wv.x, nb[0]);
                nb[1] = fmaf(av[c], wv.y, nb[1]);
                nb[2] = fmaf(av[c], wv.z, nb[2]);
                nb[3] = fmaf(av[c], wv.w, nb[3]);
            }
            #pragma unroll
            for (int o = 1; o <= 4; o <<= 1)
                #pragma unroll
                for (int hh = 0; hh < 4; ++hh)
                    nb[hh] += __shfl_xor(nb[hh], o, 64);
            if (g == 0) {
                const int i = grow >> 8, j = grow & 255;
                #pragma unroll
                for (int hh = 0; hh < 4; ++hh) {
                    size_t f = ((size_t)hh << 14) + ((size_t)(i >> 4) << 10) +
                               ((size_t)(j >> 4) << 6) + ((size_t)((j >> 2) & 3) << 4) +
                               (i & 15);
                    nbP[f * 4 + (j & 3)] = nb[hh];
                }
            }
        }
        __syncthreads();

        // ---- Phase B: projection, wave w = tensor w ----
        f32x4 acc0[8], acc1[8];
        #pragma unroll
        for (int n = 0; n < 8; ++n) {
            acc0[n] = (f32x4){0.f, 0.f, 0.f, 0.f};
            acc1[n] = (f32x4){0.f, 0.f, 0.f, 0.f};
        }
        #pragma unroll
        for (int kf = 0; kf < 4; ++kf) {
            const int ao = l15 * 136 + kf * 32 + quad * 8;
            bf16x8 A0 = *(const bf16x8*)&aH[ao];
            bf16x8 A1 = *(const bf16x8*)&aH[ao + 16 * 136];
            #pragma unroll
            for (int n = 0; n < 8; ++n) {
                bf16x8 bh = *(const bf16x8*)&Bh[(size_t)((n * 4 + kf) * 64 + lane) * 8];
                acc0[n] = mfma16(A0, bh, acc0[n]);
                acc1[n] = mfma16(A1, bh, acc1[n]);
            }
        }

        if (tensor == 3) {
            __half* const sth = (__half*)stg;
            #pragma unroll 1
            for (int s = 0; s < 2; ++s) {
                f32x4* accp = s ? acc1 : acc0;
                #pragma unroll
                for (int n = 0; n < 8; ++n)
                    #pragma unroll
                    for (int r = 0; r < 4; ++r) {
                        float v = accp[n][r] + bg[n * 16 + l15];
                        sth[(quad * 4 + r) * 136 + n * 16 + l15] =
                            (__half)(1.0f / (1.0f + __expf(-v)));
                    }
                #pragma unroll
                for (int i = 0; i < 4; ++i) {
                    int row = i * 4 + (lane >> 4);
                    int c8 = lane & 15;
                    uint4 hv = *(const uint4*)&sth[row * 136 + c8 * 8];
                    *(uint4*)&gfh[(size_t)(rc + s * 16 + row) * CCH + c8 * 8] = hv;
                }
            }
        } else {
            __bf16* const sth = (__bf16*)stg;
            __bf16* const oh = (tensor == 0) ? qb : (tensor == 1) ? kb : vb;
            #pragma unroll 1
            for (int s = 0; s < 2; ++s) {
                f32x4* accp = s ? acc1 : acc0;
                #pragma unroll
                for (int n = 0; n < 8; ++n)
                    #pragma unroll
                    for (int r = 0; r < 4; ++r)
                        sth[(quad * 4 + r) * 136 + n * 16 + l15] = (__bf16)accp[n][r];
                #pragma unroll
                for (int i = 0; i < 4; ++i) {
                    int row = i * 4 + (lane >> 4);
                    int c8 = lane & 15;
                    uint4 hv = *(const uint4*)&sth[row * 136 + c8 * 8];
                    *(uint4*)&oh[(size_t)(rc + s * 16 + row) * CCH + c8 * 8] = hv;
                }
            }
        }
        // aH is re-written by the next chunk's Phase A: wait for all waves'
        // MFMA reads (and per-wave stg use) to finish first.
        if (chunk == 0) __syncthreads();
    }
}

// ---------------- attention (single-bf16 S^T path) ----------------
__global__ __launch_bounds__(256) void attn_kernel(
    const __bf16* __restrict__ qb, const __bf16* __restrict__ kb,
    const __bf16* __restrict__ vb, const __half* __restrict__ gfh,
    const float* __restrict__ mask, const float* __restrict__ nbP,
    __bf16* __restrict__ gth, __bf16* __restrict__ gtl)
{
    __shared__ __align__(16) char smem[23040];
    __bf16* const vth = (__bf16*)smem;               // [32][264] = 16896B
    __bf16* const pbb = (__bf16*)(smem + 16896);     // [4][16][40] = 5120B
    float*  const biasrow = (float*)(smem + 22016);  // [256]
    const int t = threadIdx.x, w = t >> 6, lane = t & 63;
    const int l15 = lane & 15, quad = lane >> 4;
    const int mrow = blockIdx.x >> 2, h = blockIdx.x & 3;
    const size_t rbase = (size_t)mrow * NRES;
    const int ch0 = h * 32;

    biasrow[t] = 1e9f * (mask[mrow * NRES + t] - 1.0f);

    // V^T staging (single plane)
    #pragma unroll
    for (int it = 0; it < 4; ++it) {
        int f = t + it * 256;
        int j = f >> 2, cg = f & 3;
        bf16x8 hv = *(const bf16x8*)&vb[(rbase + j) * CCH + ch0 + cg * 8];
        #pragma unroll
        for (int e = 0; e < 8; ++e)
            vth[(cg * 8 + e) * 264 + j] = hv[e];
    }
    __syncthreads();

    const int i0 = w * 64;
    bf16x8 Qh[4];
    #pragma unroll
    for (int s = 0; s < 4; ++s)
        Qh[s] = *(const bf16x8*)&qb[(rbase + i0 + s * 16 + l15) * CCH + ch0 + quad * 8];

    f32x4 O[4][2];
    float ls[4] = {0.f, 0.f, 0.f, 0.f};
    #pragma unroll
    for (int s = 0; s < 4; ++s) {
        O[s][0] = (f32x4){0.f, 0.f, 0.f, 0.f};
        O[s][1] = (f32x4){0.f, 0.f, 0.f, 0.f};
    }
    __bf16* const ph = pbb + w * 640;

    for (int jb = 0; jb < NRES; jb += 32) {
        bf16x8 Kh[2];
        #pragma unroll
        for (int js = 0; js < 2; ++js)
            Kh[js] = *(const bf16x8*)&kb[(rbase + jb + js * 16 + l15) * CCH + ch0 + quad * 8];
        bf16x8 Vh2[2];
        #pragma unroll
        for (int c = 0; c < 2; ++c)
            Vh2[c] = *(const bf16x8*)&vth[(c * 16 + l15) * 264 + jb + quad * 8];
        #pragma unroll
        for (int s = 0; s < 4; ++s) {
            #pragma unroll
            for (int js = 0; js < 2; ++js) {
                f32x4 S = (f32x4){0.f, 0.f, 0.f, 0.f};
                S = mfma16(Kh[js], Qh[s], S);
                size_t f4 = (((size_t)(h * 16 + w * 4 + s) * 16 +
                              (jb >> 4) + js) << 6) + quad * 16 + l15;
                float4 nb4 = *(const float4*)&nbP[f4 * 4];
                float4 mb4 = *(const float4*)&biasrow[jb + js * 16 + quad * 4];
                float p0 = __expf(S[0] + nb4.x + mb4.x - 4.0f);
                float p1 = __expf(S[1] + nb4.y + mb4.y - 4.0f);
                float p2 = __expf(S[2] + nb4.z + mb4.z - 4.0f);
                float p3 = __expf(S[3] + nb4.w + mb4.w - 4.0f);
                ls[s] += (p0 + p1) + (p2 + p3);
                PK4 hh;
                hh.b[0] = (__bf16)p0; hh.b[1] = (__bf16)p1;
                hh.b[2] = (__bf16)p2; hh.b[3] = (__bf16)p3;
                *(uint2*)&ph[l15 * 40 + js * 16 + quad * 4] = hh.u2;
            }
            bf16x8 Ph = *(const bf16x8*)&ph[l15 * 40 + quad * 8];
            #pragma unroll
            for (int c = 0; c < 2; ++c)
                O[s][c] = mfma16(Vh2[c], Ph, O[s][c]);
        }
    }

    #pragma unroll
    for (int s = 0; s < 4; ++s) {
        ls[s] += __shfl_xor(ls[s], 16, 64);
        ls[s] += __shfl_xor(ls[s], 32, 64);
    }

    // epilogue: gate (fp16 g), hi/lo output via two-pass per-wave staging
    float ov[4][2][4];
    #pragma unroll
    for (int s = 0; s < 4; ++s) {
        float inv = 1.0f / ls[s];
        #pragma unroll
        for (int c = 0; c < 2; ++c) {
            size_t gi = (rbase + i0 + s * 16 + l15) * CCH + ch0 + c * 16 + quad * 4;
            uint2 gu = *(const uint2*)&gfh[gi];
            const __half* gh = (const __half*)&gu;
            #pragma unroll
            for (int r = 0; r < 4; ++r)
                ov[s][c][r] = O[s][c][r] * inv * (float)gh[r];
        }
    }
    __syncthreads();   // vth/pb dead for all waves
    __bf16* const stp = (__bf16*)(smem + w * 5120);   // [64][40]
    #pragma unroll
    for (int s = 0; s < 4; ++s)
        #pragma unroll
        for (int c = 0; c < 2; ++c) {
            PK4 hh;
            #pragma unroll
            for (int r = 0; r < 4; ++r) hh.b[r] = (__bf16)ov[s][c][r];
            *(uint2*)&stp[(s * 16 + l15) * 40 + c * 16 + quad * 4] = hh.u2;
        }
    #pragma unroll
    for (int i = 0; i < 4; ++i) {
        int row = i * 16 + (lane >> 2);
        int c8 = lane & 3;
        uint4 hv = *(const uint4*)&stp[row * 40 + c8 * 8];
        *(uint4*)&gth[(rbase + i0 + row) * CCH + ch0 + c8 * 8] = hv;
    }
    #pragma unroll
    for (int s = 0; s < 4; ++s)
        #pragma unroll
        for (int c = 0; c < 2; ++c) {
            PK4 ll;
            #pragma unroll
            for (int r = 0; r < 4; ++r) {
                __bf16 hv = (__bf16)ov[s][c][r];
                ll.b[r] = (__bf16)(ov[s][c][r] - (float)hv);
            }
            *(uint2*)&stp[(s * 16 + l15) * 40 + c * 16 + quad * 4] = ll.u2;
        }
    #pragma unroll
    for (int i = 0; i < 4; ++i) {
        int row = i * 16 + (lane >> 2);
        int c8 = lane & 3;
        uint4 lv = *(const uint4*)&stp[row * 40 + c8 * 8];
        *(uint4*)&gtl[(rbase + i0 + row) * CCH + ch0 + c8 * 8] = lv;
    }
}

// ---------------- output GEMM (split MFMA): gated @ wo + bo -> fp32 --------
__global__ __launch_bounds__(256) void out_kernel(
    const __bf16* __restrict__ gth, const __bf16* __restrict__ gtl,
    const __bf16* __restrict__ wph, const __bf16* __restrict__ wpl,
    const float* __restrict__ bo, float* __restrict__ out)
{
    __shared__ __align__(16) float eps[4][16 * 132];
    const int t = threadIdx.x, w = t >> 6, lane = t & 63;
    const int l15 = lane & 15, quad = lane >> 4;
    const int r0 = blockIdx.x * 64 + w * 16;
    const __bf16* __restrict__ Bh = wph + (size_t)4 * 16384;
    const __bf16* __restrict__ Bl = wpl + (size_t)4 * 16384;

    f32x4 acc[8];
    #pragma unroll
    for (int n = 0; n < 8; ++n) acc[n] = (f32x4){0.f, 0.f, 0.f, 0.f};

    #pragma unroll
    for (int kf = 0; kf < 4; ++kf) {
        size_t idx = (size_t)(r0 + l15) * CCH + kf * 32 + quad * 8;
        bf16x8 Ahf = *(const bf16x8*)&gth[idx];
        bf16x8 Alf = *(const bf16x8*)&gtl[idx];
        #pragma unroll
        for (int n = 0; n < 8; ++n) {
            size_t boff = (size_t)((n * 4 + kf) * 64 + lane) * 8;
            bf16x8 bh = *(const bf16x8*)&Bh[boff];
            bf16x8 bl = *(const bf16x8*)&Bl[boff];
            acc[n] = mfma16(Ahf, bh, acc[n]);
            acc[n] = mfma16(Ahf, bl, acc[n]);
            acc[n] = mfma16(Alf, bh, acc[n]);
        }
    }

    #pragma unroll
    for (int n = 0; n < 8; ++n)
        #pragma unroll
        for (int r = 0; r < 4; ++r)
            eps[w][(quad * 4 + r) * 132 + n * 16 + l15] = acc[n][r];
    const int erow = lane >> 2;
    const int ecg0 = lane & 3;
    #pragma unroll
    for (int it = 0; it < 8; ++it) {
        int cg = ecg0 + it * 4;
        float4 v4 = *(const float4*)&eps[w][erow * 132 + cg * 4];
        float4 b4 = *(const float4*)&bo[cg * 4];
        v4.x += b4.x; v4.y += b4.y; v4.z += b4.z; v4.w += b4.w;
        *(float4*)&out[(size_t)(r0 + erow) * CCH + cg * 4] = v4;
    }
}

extern "C" void kernel_launch(void* const* d_in, const int* in_sizes, int n_in,
                              void* d_out, int out_size, void* d_ws, size_t ws_size,
                              hipStream_t stream)
{
    const float* act  = (const float*)d_in[0];
    const float* mask = (const float*)d_in[1];
    const float* ln_g = (const float*)d_in[2];
    const float* ln_b = (const float*)d_in[3];
    const float* wq   = (const float*)d_in[4];
    const float* wk   = (const float*)d_in[5];
    const float* wv   = (const float*)d_in[6];
    const float* w2d  = (const float*)d_in[7];
    const float* wg   = (const float*)d_in[8];
    const float* bg   = (const float*)d_in[9];
    const float* wo   = (const float*)d_in[10];
    const float* bo   = (const float*)d_in[11];
    float* out = (float*)d_out;

    const size_t SZ = (size_t)NROWS * CCH;   // 8388608 elems
    __bf16* bws = (__bf16*)d_ws;
    __bf16* qb  = bws;
    __bf16* kb  = bws + SZ;
    __bf16* vb  = bws + 2 * SZ;
    __bf16* gth = bws + 3 * SZ;
    __bf16* gtl = bws + 4 * SZ;
    __half* gfh = (__half*)(bws + 5 * SZ);     // SZ halves
    float* nbP = (float*)(bws + 6 * SZ);       // 4*NROWS floats
    __bf16* wph = (__bf16*)(nbP + 4 * NROWS);  // 5*16384 bf16
    __bf16* wpl = wph + 5 * 16384;

    prep_kernel<<<40, 256, 0, stream>>>(wq, wk, wv, wg, wo, wph, wpl);
    lnproj_kernel<<<1024, 256, 0, stream>>>(
        act, ln_g, ln_b, w2d, wph, bg, qb, kb, vb, gfh, nbP);
    attn_kernel<<<NRES * 4, 256, 0, stream>>>(
        qb, kb, vb, gfh, mask, nbP, gth, gtl);
    out_kernel<<<1024, 256, 0, stream>>>(gth, gtl, wph, wpl, bo, out);
}

// Round 2
// 204.750 us; speedup vs baseline: 1.0079x; 1.0079x over previous
//
#include <hip/hip_runtime.h>
#include <hip/hip_fp16.h>
#include <math.h>

// TriangleAttentionStartingNode: B=1, N=256, C=128, H=4, AC=32, fp32 in/out.
// R6: precision-lite pipeline (see prior notes).
// R7 FAILED: __launch_bounds__(256,4) forced VGPR=64 -> spilled the
//   prefetch (FETCH +15MB, WRITE +30MB scratch traffic), dur unchanged.
//   Also proved occupancy is not the lever (17%->38%, same 64.8us).
// R8: zero-barrier lnproj. Each wave owns 32 rows and computes ALL four
//   tensors for them in a wave-private LDS region ([32][136] bf16, 8.7KB).
//   LN-write -> A-frag-read is a same-wave LDS dep (lgkmcnt, no
//   __syncthreads); A-frags hoisted to regs, LDS recycled as epilogue
//   staging. 4 waves/block fully decoupled -> phase skew hides HBM
//   latency; B-frags keep 2x reuse (two 16-row A sets per wave).

#define NRES 256
#define CCH  128
#define NROWS (NRES * NRES)          // 65536
#define FACTOR 0.17677669529663687f  // 1/sqrt(32)

typedef __attribute__((ext_vector_type(8))) __bf16 bf16x8;
typedef __attribute__((ext_vector_type(4))) float f32x4;

__device__ __forceinline__ f32x4 mfma16(bf16x8 a, bf16x8 b, f32x4 c) {
    return __builtin_amdgcn_mfma_f32_16x16x32_bf16(a, b, c, 0, 0, 0);
}

union PK4 { __bf16 b[4]; uint2 u2; };
union PK2 { __bf16 b[2]; unsigned int u; };

__device__ __forceinline__ void hilo(float x, __bf16& h, __bf16& l) {
    h = (__bf16)x;
    l = (__bf16)(x - (float)h);
}

// ---------------- weight prep: pack into B-frag layout ----------------
// hi planes used by lnproj (single-MFMA GEMMs); lo planes only read for wo.
__global__ __launch_bounds__(256) void prep_kernel(
    const float* __restrict__ wq, const float* __restrict__ wk,
    const float* __restrict__ wv, const float* __restrict__ wg,
    const float* __restrict__ wo,
    __bf16* __restrict__ wph, __bf16* __restrict__ wpl)
{
    const int gid = blockIdx.x * 256 + threadIdx.x;   // 0..10239
    const int wid = gid >> 11;
    const int rem = gid & 2047;
    const int nstrip = rem >> 8;
    const int kf = (rem >> 6) & 3;
    const int lane = rem & 63;
    const int l15 = lane & 15, quad = lane >> 4;
    const float* W = (wid == 0) ? wq : (wid == 1) ? wk :
                     (wid == 2) ? wv : (wid == 3) ? wg : wo;
    const float scale = (wid == 0) ? FACTOR : 1.0f;
    bf16x8 hb, lb;
    #pragma unroll
    for (int e = 0; e < 8; ++e) {
        int k = kf * 32 + quad * 8 + e;
        int n = nstrip * 16 + l15;
        float v = W[k * CCH + n] * scale;
        __bf16 h, l; hilo(v, h, l);
        hb[e] = h; lb[e] = l;
    }
    *(bf16x8*)&wph[(size_t)gid * 8] = hb;
    *(bf16x8*)&wpl[(size_t)gid * 8] = lb;
}

// ---------------- fused LN + nb + projection (zero-barrier) ----------------
// Each wave: 32 rows, all 4 tensors, wave-private LDS. No __syncthreads.
__global__ __launch_bounds__(256) void lnproj_kernel(
    const float* __restrict__ act, const float* __restrict__ ln_g,
    const float* __restrict__ ln_b, const float* __restrict__ w2d,
    const __bf16* __restrict__ wph, const float* __restrict__ bg,
    __bf16* __restrict__ qb, __bf16* __restrict__ kb,
    __bf16* __restrict__ vb, __half* __restrict__ gfh,
    float* __restrict__ nbP)
{
    __shared__ __align__(16) char smem[34816];       // 4 x 8704B wave-private
    const int t = threadIdx.x, w = t >> 6, lane = t & 63;
    const int l15 = lane & 15, quad = lane >> 4;
    __bf16* const aH = (__bf16*)(smem + w * 8704);   // [32][136] bf16
    const int r0w = blockIdx.x * 128 + w * 32;

    // ---- Phase A: LayerNorm + nb (2 lanes/row, 64 ch each) ----
    {
        const int row = lane >> 1, half = lane & 1;
        const int grow = r0w + row;
        const float* __restrict__ xp = act + (size_t)grow * CCH + half * 64;
        float4 x4[16];
        #pragma unroll
        for (int c = 0; c < 16; ++c) x4[c] = *(const float4*)(xp + c * 4);
        float s = 0.f, sq = 0.f;
        #pragma unroll
        for (int c = 0; c < 16; ++c) {
            s  += (x4[c].x + x4[c].y) + (x4[c].z + x4[c].w);
            sq += x4[c].x * x4[c].x + x4[c].y * x4[c].y +
                  x4[c].z * x4[c].z + x4[c].w * x4[c].w;
        }
        s  += __shfl_xor(s, 1, 64);
        sq += __shfl_xor(sq, 1, 64);
        float mu  = s * (1.0f / CCH);
        float var = fmaf(sq, 1.0f / CCH, -mu * mu);
        float rs  = rsqrtf(var + 1e-5f);
        float nb[4] = {0.f, 0.f, 0.f, 0.f};
        const float4* __restrict__ w2d4 = (const float4*)w2d;
        #pragma unroll
        for (int c2 = 0; c2 < 8; ++c2) {
            bf16x8 pk;
            #pragma unroll
            for (int cc = 0; cc < 2; ++cc) {
                const int c = c2 * 2 + cc;
                float4 g4 = *(const float4*)&ln_g[half * 64 + c * 4];
                float4 b4 = *(const float4*)&ln_b[half * 64 + c * 4];
                float* xv = (float*)&x4[c];
                float* gv = (float*)&g4;
                float* bv = (float*)&b4;
                #pragma unroll
                for (int e = 0; e < 4; ++e) {
                    float av = fmaf((xv[e] - mu) * rs, gv[e], bv[e]);
                    pk[cc * 4 + e] = (__bf16)av;
                    float4 wv = w2d4[half * 64 + c * 4 + e];
                    nb[0] = fmaf(av, wv.x, nb[0]);
                    nb[1] = fmaf(av, wv.y, nb[1]);
                    nb[2] = fmaf(av, wv.z, nb[2]);
                    nb[3] = fmaf(av, wv.w, nb[3]);
                }
            }
            *(bf16x8*)&aH[row * 136 + half * 64 + c2 * 8] = pk;
        }
        #pragma unroll
        for (int hh = 0; hh < 4; ++hh)
            nb[hh] += __shfl_xor(nb[hh], 1, 64);
        if (half == 0) {
            const int i = grow >> 8, j = grow & 255;
            #pragma unroll
            for (int hh = 0; hh < 4; ++hh) {
                size_t f = ((size_t)hh << 14) + ((size_t)(i >> 4) << 10) +
                           ((size_t)(j >> 4) << 6) + ((size_t)((j >> 2) & 3) << 4) +
                           (i & 15);
                nbP[f * 4 + (j & 3)] = nb[hh];
            }
        }
    }

    // ---- A-frags to regs (same-wave LDS dep; compiler inserts lgkmcnt).
    // aH becomes dead afterwards -> recycled as epilogue staging plane.
    bf16x8 A0[4], A1[4];
    #pragma unroll
    for (int kf = 0; kf < 4; ++kf) {
        const int ao = l15 * 136 + kf * 32 + quad * 8;
        A0[kf] = *(const bf16x8*)&aH[ao];
        A1[kf] = *(const bf16x8*)&aH[ao + 16 * 136];
    }

    // ---- Phase B: all 4 tensors for this wave's 32 rows ----
    #pragma unroll 1
    for (int tn = 0; tn < 4; ++tn) {
        const __bf16* __restrict__ Bh = wph + (size_t)tn * 16384;
        f32x4 acc0[8], acc1[8];
        #pragma unroll
        for (int n = 0; n < 8; ++n) {
            acc0[n] = (f32x4){0.f, 0.f, 0.f, 0.f};
            acc1[n] = (f32x4){0.f, 0.f, 0.f, 0.f};
        }
        #pragma unroll
        for (int kf = 0; kf < 4; ++kf)
            #pragma unroll
            for (int n = 0; n < 8; ++n) {
                bf16x8 bh = *(const bf16x8*)&Bh[(size_t)((n * 4 + kf) * 64 + lane) * 8];
                acc0[n] = mfma16(A0[kf], bh, acc0[n]);
                acc1[n] = mfma16(A1[kf], bh, acc1[n]);
            }

        if (tn == 3) {
            __half* const sth = (__half*)aH;     // recycled staging [16][136]
            #pragma unroll 1
            for (int sp = 0; sp < 2; ++sp) {
                f32x4* accp = sp ? acc1 : acc0;
                #pragma unroll
                for (int n = 0; n < 8; ++n)
                    #pragma unroll
                    for (int r = 0; r < 4; ++r) {
                        float v = accp[n][r] + bg[n * 16 + l15];
                        sth[(quad * 4 + r) * 136 + n * 16 + l15] =
                            (__half)(1.0f / (1.0f + __expf(-v)));
                    }
                #pragma unroll
                for (int i = 0; i < 4; ++i) {
                    int row = i * 4 + (lane >> 4);
                    int c8 = lane & 15;
                    uint4 hv = *(const uint4*)&sth[row * 136 + c8 * 8];
                    *(uint4*)&gfh[(size_t)(r0w + sp * 16 + row) * CCH + c8 * 8] = hv;
                }
            }
        } else {
            __bf16* const sth = (__bf16*)aH;     // recycled staging [16][136]
            __bf16* const oh = (tn == 0) ? qb : (tn == 1) ? kb : vb;
            #pragma unroll 1
            for (int sp = 0; sp < 2; ++sp) {
                f32x4* accp = sp ? acc1 : acc0;
                #pragma unroll
                for (int n = 0; n < 8; ++n)
                    #pragma unroll
                    for (int r = 0; r < 4; ++r)
                        sth[(quad * 4 + r) * 136 + n * 16 + l15] = (__bf16)accp[n][r];
                #pragma unroll
                for (int i = 0; i < 4; ++i) {
                    int row = i * 4 + (lane >> 4);
                    int c8 = lane & 15;
                    uint4 hv = *(const uint4*)&sth[row * 136 + c8 * 8];
                    *(uint4*)&oh[(size_t)(r0w + sp * 16 + row) * CCH + c8 * 8] = hv;
                }
            }
        }
    }
}

// ---------------- attention (single-bf16 S^T path) ----------------
__global__ __launch_bounds__(256) void attn_kernel(
    const __bf16* __restrict__ qb, const __bf16* __restrict__ kb,
    const __bf16* __restrict__ vb, const __half* __restrict__ gfh,
    const float* __restrict__ mask, const float* __restrict__ nbP,
    __bf16* __restrict__ gth, __bf16* __restrict__ gtl)
{
    __shared__ __align__(16) char smem[23040];
    __bf16* const vth = (__bf16*)smem;               // [32][264] = 16896B
    __bf16* const pbb = (__bf16*)(smem + 16896);     // [4][16][40] = 5120B
    float*  const biasrow = (float*)(smem + 22016);  // [256]
    const int t = threadIdx.x, w = t >> 6, lane = t & 63;
    const int l15 = lane & 15, quad = lane >> 4;
    const int mrow = blockIdx.x >> 2, h = blockIdx.x & 3;
    const size_t rbase = (size_t)mrow * NRES;
    const int ch0 = h * 32;

    biasrow[t] = 1e9f * (mask[mrow * NRES + t] - 1.0f);

    // V^T staging (single plane)
    #pragma unroll
    for (int it = 0; it < 4; ++it) {
        int f = t + it * 256;
        int j = f >> 2, cg = f & 3;
        bf16x8 hv = *(const bf16x8*)&vb[(rbase + j) * CCH + ch0 + cg * 8];
        #pragma unroll
        for (int e = 0; e < 8; ++e)
            vth[(cg * 8 + e) * 264 + j] = hv[e];
    }
    __syncthreads();

    const int i0 = w * 64;
    bf16x8 Qh[4];
    #pragma unroll
    for (int s = 0; s < 4; ++s)
        Qh[s] = *(const bf16x8*)&qb[(rbase + i0 + s * 16 + l15) * CCH + ch0 + quad * 8];

    f32x4 O[4][2];
    float ls[4] = {0.f, 0.f, 0.f, 0.f};
    #pragma unroll
    for (int s = 0; s < 4; ++s) {
        O[s][0] = (f32x4){0.f, 0.f, 0.f, 0.f};
        O[s][1] = (f32x4){0.f, 0.f, 0.f, 0.f};
    }
    __bf16* const ph = pbb + w * 640;

    for (int jb = 0; jb < NRES; jb += 32) {
        bf16x8 Kh[2];
        #pragma unroll
        for (int js = 0; js < 2; ++js)
            Kh[js] = *(const bf16x8*)&kb[(rbase + jb + js * 16 + l15) * CCH + ch0 + quad * 8];
        bf16x8 Vh2[2];
        #pragma unroll
        for (int c = 0; c < 2; ++c)
            Vh2[c] = *(const bf16x8*)&vth[(c * 16 + l15) * 264 + jb + quad * 8];
        #pragma unroll
        for (int s = 0; s < 4; ++s) {
            #pragma unroll
            for (int js = 0; js < 2; ++js) {
                f32x4 S = (f32x4){0.f, 0.f, 0.f, 0.f};
                S = mfma16(Kh[js], Qh[s], S);
                size_t f4 = (((size_t)(h * 16 + w * 4 + s) * 16 +
                              (jb >> 4) + js) << 6) + quad * 16 + l15;
                float4 nb4 = *(const float4*)&nbP[f4 * 4];
                float4 mb4 = *(const float4*)&biasrow[jb + js * 16 + quad * 4];
                float p0 = __expf(S[0] + nb4.x + mb4.x - 4.0f);
                float p1 = __expf(S[1] + nb4.y + mb4.y - 4.0f);
                float p2 = __expf(S[2] + nb4.z + mb4.z - 4.0f);
                float p3 = __expf(S[3] + nb4.w + mb4.w - 4.0f);
                ls[s] += (p0 + p1) + (p2 + p3);
                PK4 hh;
                hh.b[0] = (__bf16)p0; hh.b[1] = (__bf16)p1;
                hh.b[2] = (__bf16)p2; hh.b[3] = (__bf16)p3;
                *(uint2*)&ph[l15 * 40 + js * 16 + quad * 4] = hh.u2;
            }
            bf16x8 Ph = *(const bf16x8*)&ph[l15 * 40 + quad * 8];
            #pragma unroll
            for (int c = 0; c < 2; ++c)
                O[s][c] = mfma16(Vh2[c], Ph, O[s][c]);
        }
    }

    #pragma unroll
    for (int s = 0; s < 4; ++s) {
        ls[s] += __shfl_xor(ls[s], 16, 64);
        ls[s] += __shfl_xor(ls[s], 32, 64);
    }

    // epilogue: gate (fp16 g), hi/lo output via two-pass per-wave staging
    float ov[4][2][4];
    #pragma unroll
    for (int s = 0; s < 4; ++s) {
        float inv = 1.0f / ls[s];
        #pragma unroll
        for (int c = 0; c < 2; ++c) {
            size_t gi = (rbase + i0 + s * 16 + l15) * CCH + ch0 + c * 16 + quad * 4;
            uint2 gu = *(const uint2*)&gfh[gi];
            const __half* gh = (const __half*)&gu;
            #pragma unroll
            for (int r = 0; r < 4; ++r)
                ov[s][c][r] = O[s][c][r] * inv * (float)gh[r];
        }
    }
    __syncthreads();   // vth/pb dead for all waves
    __bf16* const stp = (__bf16*)(smem + w * 5120);   // [64][40]
    #pragma unroll
    for (int s = 0; s < 4; ++s)
        #pragma unroll
        for (int c = 0; c < 2; ++c) {
            PK4 hh;
            #pragma unroll
            for (int r = 0; r < 4; ++r) hh.b[r] = (__bf16)ov[s][c][r];
            *(uint2*)&stp[(s * 16 + l15) * 40 + c * 16 + quad * 4] = hh.u2;
        }
    #pragma unroll
    for (int i = 0; i < 4; ++i) {
        int row = i * 16 + (lane >> 2);
        int c8 = lane & 3;
        uint4 hv = *(const uint4*)&stp[row * 40 + c8 * 8];
        *(uint4*)&gth[(rbase + i0 + row) * CCH + ch0 + c8 * 8] = hv;
    }
    #pragma unroll
    for (int s = 0; s < 4; ++s)
        #pragma unroll
        for (int c = 0; c < 2; ++c) {
            PK4 ll;
            #pragma unroll
            for (int r = 0; r < 4; ++r) {
                __bf16 hv = (__bf16)ov[s][c][r];
                ll.b[r] = (__bf16)(ov[s][c][r] - (float)hv);
            }
            *(uint2*)&stp[(s * 16 + l15) * 40 + c * 16 + quad * 4] = ll.u2;
        }
    #pragma unroll
    for (int i = 0; i < 4; ++i) {
        int row = i * 16 + (lane >> 2);
        int c8 = lane & 3;
        uint4 lv = *(const uint4*)&stp[row * 40 + c8 * 8];
        *(uint4*)&gtl[(rbase + i0 + row) * CCH + ch0 + c8 * 8] = lv;
    }
}

// ---------------- output GEMM (split MFMA): gated @ wo + bo -> fp32 --------
__global__ __launch_bounds__(256) void out_kernel(
    const __bf16* __restrict__ gth, const __bf16* __restrict__ gtl,
    const __bf16* __restrict__ wph, const __bf16* __restrict__ wpl,
    const float* __restrict__ bo, float* __restrict__ out)
{
    __shared__ __align__(16) float eps[4][16 * 132];
    const int t = threadIdx.x, w = t >> 6, lane = t & 63;
    const int l15 = lane & 15, quad = lane >> 4;
    const int r0 = blockIdx.x * 64 + w * 16;
    const __bf16* __restrict__ Bh = wph + (size_t)4 * 16384;
    const __bf16* __restrict__ Bl = wpl + (size_t)4 * 16384;

    f32x4 acc[8];
    #pragma unroll
    for (int n = 0; n < 8; ++n) acc[n] = (f32x4){0.f, 0.f, 0.f, 0.f};

    #pragma unroll
    for (int kf = 0; kf < 4; ++kf) {
        size_t idx = (size_t)(r0 + l15) * CCH + kf * 32 + quad * 8;
        bf16x8 Ahf = *(const bf16x8*)&gth[idx];
        bf16x8 Alf = *(const bf16x8*)&gtl[idx];
        #pragma unroll
        for (int n = 0; n < 8; ++n) {
            size_t boff = (size_t)((n * 4 + kf) * 64 + lane) * 8;
            bf16x8 bh = *(const bf16x8*)&Bh[boff];
            bf16x8 bl = *(const bf16x8*)&Bl[boff];
            acc[n] = mfma16(Ahf, bh, acc[n]);
            acc[n] = mfma16(Ahf, bl, acc[n]);
            acc[n] = mfma16(Alf, bh, acc[n]);
        }
    }

    #pragma unroll
    for (int n = 0; n < 8; ++n)
        #pragma unroll
        for (int r = 0; r < 4; ++r)
            eps[w][(quad * 4 + r) * 132 + n * 16 + l15] = acc[n][r];
    const int erow = lane >> 2;
    const int ecg0 = lane & 3;
    #pragma unroll
    for (int it = 0; it < 8; ++it) {
        int cg = ecg0 + it * 4;
        float4 v4 = *(const float4*)&eps[w][erow * 132 + cg * 4];
        float4 b4 = *(const float4*)&bo[cg * 4];
        v4.x += b4.x; v4.y += b4.y; v4.z += b4.z; v4.w += b4.w;
        *(float4*)&out[(size_t)(r0 + erow) * CCH + cg * 4] = v4;
    }
}

extern "C" void kernel_launch(void* const* d_in, const int* in_sizes, int n_in,
                              void* d_out, int out_size, void* d_ws, size_t ws_size,
                              hipStream_t stream)
{
    const float* act  = (const float*)d_in[0];
    const float* mask = (const float*)d_in[1];
    const float* ln_g = (const float*)d_in[2];
    const float* ln_b = (const float*)d_in[3];
    const float* wq   = (const float*)d_in[4];
    const float* wk   = (const float*)d_in[5];
    const float* wv   = (const float*)d_in[6];
    const float* w2d  = (const float*)d_in[7];
    const float* wg   = (const float*)d_in[8];
    const float* bg   = (const float*)d_in[9];
    const float* wo   = (const float*)d_in[10];
    const float* bo   = (const float*)d_in[11];
    float* out = (float*)d_out;

    const size_t SZ = (size_t)NROWS * CCH;   // 8388608 elems
    __bf16* bws = (__bf16*)d_ws;
    __bf16* qb  = bws;
    __bf16* kb  = bws + SZ;
    __bf16* vb  = bws + 2 * SZ;
    __bf16* gth = bws + 3 * SZ;
    __bf16* gtl = bws + 4 * SZ;
    __half* gfh = (__half*)(bws + 5 * SZ);     // SZ halves
    float* nbP = (float*)(bws + 6 * SZ);       // 4*NROWS floats
    __bf16* wph = (__bf16*)(nbP + 4 * NROWS);  // 5*16384 bf16
    __bf16* wpl = wph + 5 * 16384;

    prep_kernel<<<40, 256, 0, stream>>>(wq, wk, wv, wg, wo, wph, wpl);
    lnproj_kernel<<<512, 256, 0, stream>>>(
        act, ln_g, ln_b, w2d, wph, bg, qb, kb, vb, gfh, nbP);
    attn_kernel<<<NRES * 4, 256, 0, stream>>>(
        qb, kb, vb, gfh, mask, nbP, gth, gtl);
    out_kernel<<<1024, 256, 0, stream>>>(gth, gtl, wph, wpl, bo, out);
}